// Round 4
// baseline (28.887 us; speedup 1.0000x reference)
//
#include <hip/hip_runtime.h>

// Problem constants (from reference): B=8, TIMES=288, N=207, D=64, FEA_IN=295
#define B_     8
#define TIMES_ 288
#define NN_    207
#define D_     64
#define BT_    (B_ * TIMES_)   // 2304

typedef float f4_t __attribute__((ext_vector_type(4)));

// K1: compute all BT_ rows into ws. 256 threads = 4 groups of 64; each group
// handles one bt. grid = BT_/4 = 576 blocks.
__global__ __launch_bounds__(256) void tem_compute_rows(
    const int*   __restrict__ TE,   // (B, TIMES, N, 2) int32
    const float* __restrict__ W1,   // (295, 64)
    const float* __restrict__ b1,   // (64,)
    const float* __restrict__ W2,   // (64, 64)
    const float* __restrict__ b2,   // (64,)
    float*       __restrict__ ws)   // (BT_, 64)
{
    __shared__ float h[4][D_];
    const int tid  = threadIdx.x;
    const int grp  = tid >> 6;      // 0..3
    const int lane = tid & 63;
    const int bt   = blockIdx.x * 4 + grp;

    // te = TE[b, t, 0, :]
    const int2 te = *(const int2*)(TE + (long long)bt * (NN_ * 2));
    int dow = te.x % 7;   if (dow < 0) dow += 7;
    int tod = te.y % 288; if (tod < 0) tod += 288;

    float v = W1[dow * D_ + lane] + W1[(7 + tod) * D_ + lane] + b1[lane];
    h[grp][lane] = v > 0.0f ? v : 0.0f;
    __syncthreads();

    float acc = b2[lane];
    #pragma unroll
    for (int j = 0; j < D_; ++j) {
        acc = fmaf(h[grp][j], W2[j * D_ + lane], acc);  // coalesced, L2-hit
    }
    ws[bt * D_ + lane] = acc;
}

// K2: pure broadcast stream. One block per bt; prologue is a single 16B load.
__global__ __launch_bounds__(256) void tem_broadcast(
    const float* __restrict__ ws,   // (BT_, 64)
    float*       __restrict__ out)  // (B, TIMES, N, 64)
{
    const int bt  = blockIdx.x;
    const int tid = threadIdx.x;

    // (tid + k*256) & 15 == tid & 15 -> source float4 is loop-invariant.
    const f4_t val = ((const f4_t*)ws)[bt * (D_ / 4) + (tid & 15)];

    f4_t* out4 = (f4_t*)(out + (long long)bt * (NN_ * D_));
    const int total4 = NN_ * (D_ / 4);   // 3312
    #pragma unroll 4
    for (int i = tid; i < total4; i += 256) {
        out4[i] = val;
    }
}

// Fallback fused kernel (used only if ws is unexpectedly tiny).
__global__ __launch_bounds__(256) void tem_fused(
    const int* __restrict__ TE, const float* __restrict__ W1,
    const float* __restrict__ b1, const float* __restrict__ W2,
    const float* __restrict__ b2, float* __restrict__ out)
{
    __shared__ float h[D_];
    __shared__ float row[D_];
    const int bt  = blockIdx.x;
    const int tid = threadIdx.x;
    const int2 te = *(const int2*)(TE + (long long)bt * (NN_ * 2));
    int dow = te.x % 7;   if (dow < 0) dow += 7;
    int tod = te.y % 288; if (tod < 0) tod += 288;
    if (tid < D_) {
        float v = W1[dow * D_ + tid] + W1[(7 + tod) * D_ + tid] + b1[tid];
        h[tid] = v > 0.0f ? v : 0.0f;
    }
    __syncthreads();
    if (tid < D_) {
        float acc = b2[tid];
        #pragma unroll
        for (int j = 0; j < D_; ++j) acc = fmaf(h[j], W2[j * D_ + tid], acc);
        row[tid] = acc;
    }
    __syncthreads();
    const f4_t val = ((const f4_t*)row)[tid & 15];
    f4_t* out4 = (f4_t*)(out + (long long)bt * (NN_ * D_));
    for (int i = tid; i < NN_ * (D_ / 4); i += 256) out4[i] = val;
}

extern "C" void kernel_launch(void* const* d_in, const int* in_sizes, int n_in,
                              void* d_out, int out_size, void* d_ws, size_t ws_size,
                              hipStream_t stream) {
    const int*   TE = (const int*)  d_in[0];
    const float* W1 = (const float*)d_in[1];
    const float* b1 = (const float*)d_in[2];
    const float* W2 = (const float*)d_in[3];
    const float* b2 = (const float*)d_in[4];
    // d_in[5] is T=288 (scalar) — baked into the modulo above.
    float* out = (float*)d_out;

    const size_t ws_needed = (size_t)BT_ * D_ * sizeof(float);  // 589,824 B
    if (ws_size >= ws_needed) {
        float* rows = (float*)d_ws;
        tem_compute_rows<<<dim3(BT_ / 4), dim3(256), 0, stream>>>(TE, W1, b1, W2, b2, rows);
        tem_broadcast  <<<dim3(BT_),     dim3(256), 0, stream>>>(rows, out);
    } else {
        tem_fused<<<dim3(BT_), dim3(256), 0, stream>>>(TE, W1, b1, W2, b2, out);
    }
}

// Round 5
// 25.432 us; speedup vs baseline: 1.1359x; 1.1359x over previous
//
#include <hip/hip_runtime.h>

// Problem constants (from reference): B=8, TIMES=288, N=207, D=64, FEA_IN=295
#define B_     8
#define TIMES_ 288
#define NN_    207
#define D_     64
#define BT_    (B_ * TIMES_)   // 2304

typedef float f4_t __attribute__((ext_vector_type(4)));

// One WAVE (64 threads) per (b,t). grid = 2304 = 9 blocks/CU on 256 CUs,
// all resident simultaneously -> no straggler tail. No LDS, no barriers,
// no idle lanes:
//   h[tid]   = relu(W1[dow,tid] + W1[7+tod,tid] + b1[tid])     (register)
//   acc[tid] = b2[tid] + sum_j shfl(h,j) * W2[j,tid]           (readlane+FMA)
//   val      = float4 of row at (tid&15) via 4 shuffles
//   stream val to out[bt, 0..N-1, :] as global_store_dwordx4.
__global__ __launch_bounds__(64) void TemEmbedding_45672682225716_kernel(
    const int*   __restrict__ TE,   // (B, TIMES, N, 2) int32
    const float* __restrict__ W1,   // (295, 64)
    const float* __restrict__ b1,   // (64,)
    const float* __restrict__ W2,   // (64, 64)
    const float* __restrict__ b2,   // (64,)
    float*       __restrict__ out)  // (B, TIMES, N, 64)
{
    const int bt  = blockIdx.x;
    const int tid = threadIdx.x;    // 0..63 (one wave)

    // te = TE[b, t, 0, :] — 8B load, 8B-aligned (bt*1656 is a multiple of 8)
    const int2 te = *(const int2*)(TE + (long long)bt * (NN_ * 2));
    int dow = te.x % 7;   if (dow < 0) dow += 7;
    int tod = te.y % 288; if (tod < 0) tod += 288;

    float v = W1[dow * D_ + tid] + W1[(7 + tod) * D_ + tid] + b1[tid];
    const float hval = v > 0.0f ? v : 0.0f;

    // 64x64 matvec: h[j] is wave-uniform per j -> readlane broadcast.
    float acc = b2[tid];
    #pragma unroll
    for (int j = 0; j < D_; ++j) {
        acc = fmaf(__shfl(hval, j), W2[j * D_ + tid], acc);  // W2 L2-resident
    }

    // Assemble this thread's loop-invariant output float4: row[4*(tid&15)+c].
    const int s = (tid & 15) * 4;
    f4_t val;
    val.x = __shfl(acc, s + 0);
    val.y = __shfl(acc, s + 1);
    val.z = __shfl(acc, s + 2);
    val.w = __shfl(acc, s + 3);

    // (tid + k*64) & 15 == tid & 15 -> pure store stream, 51-52 iters/thread.
    f4_t* out4 = (f4_t*)(out + (long long)bt * (NN_ * D_));
    const int total4 = NN_ * (D_ / 4);   // 3312
    #pragma unroll 4
    for (int i = tid; i < total4; i += 64) {
        out4[i] = val;
    }
}

extern "C" void kernel_launch(void* const* d_in, const int* in_sizes, int n_in,
                              void* d_out, int out_size, void* d_ws, size_t ws_size,
                              hipStream_t stream) {
    const int*   TE = (const int*)  d_in[0];
    const float* W1 = (const float*)d_in[1];
    const float* b1 = (const float*)d_in[2];
    const float* W2 = (const float*)d_in[3];
    const float* b2 = (const float*)d_in[4];
    // d_in[5] is T=288 (scalar) — baked into the modulo above.
    float* out = (float*)d_out;

    TemEmbedding_45672682225716_kernel<<<dim3(BT_), dim3(64), 0, stream>>>(
        TE, W1, b1, W2, b2, out);
}